// Round 3
// baseline (256.432 us; speedup 1.0000x reference)
//
#include <hip/hip_runtime.h>

using uint = unsigned int;
using ushort = unsigned short;

typedef __attribute__((ext_vector_type(8))) short bf16x8;
typedef __attribute__((ext_vector_type(4))) short bf16x4;
typedef __attribute__((ext_vector_type(4))) float f32x4;

#define ADMM_ITERS 100
#define RHO_C 1.0f
#define SIGMA_C 1e-6f

__device__ inline ushort f2bf(float f) {
  union { float f; uint u; } c; c.f = f;
  uint u = c.u;
  uint r = (u + 0x7fffu + ((u >> 16) & 1u)) >> 16;
  return (ushort)r;
}

__device__ inline void gload_lds16(const void* g, void* l) {
  __builtin_amdgcn_global_load_lds(
      (const __attribute__((address_space(1))) void*)g,
      (__attribute__((address_space(3))) void*)l, 16, 0, 0);
}

// Split 8 f32 -> hi/lo bf16x8 by TRUNCATION (hi = mantissa-masked; lo = exact
// residual, truncated). Residual error ~2^-16 relative.
__device__ inline void splitPack(const float* x, bf16x8& hi, bf16x8& lo) {
#pragma unroll
  for (int j = 0; j < 8; ++j) {
    uint b = __float_as_uint(x[j]);
    uint hb = b & 0xffff0000u;
    float lf = x[j] - __uint_as_float(hb);
    hi[j] = (short)(b >> 16);
    lo[j] = (short)(__float_as_uint(lf) >> 16);
  }
}

// 4-wide truncation split with explicit v_perm_b32 packing (bit-identical to
// splitPack, ~12 VALU instead of ~24: perm grabs hi16 of two f32s per instr).
__device__ inline void splitPack4(const f32x4& x, bf16x4& hi, bf16x4& lo) {
  uint b0 = __float_as_uint(x[0]), b1 = __float_as_uint(x[1]);
  uint b2 = __float_as_uint(x[2]), b3 = __float_as_uint(x[3]);
  float l0 = x[0] - __uint_as_float(b0 & 0xffff0000u);
  float l1 = x[1] - __uint_as_float(b1 & 0xffff0000u);
  float l2 = x[2] - __uint_as_float(b2 & 0xffff0000u);
  float l3 = x[3] - __uint_as_float(b3 & 0xffff0000u);
  union { uint u[2]; bf16x4 v; } ch, cl;
  ch.u[0] = __builtin_amdgcn_perm(b1, b0, 0x07060302u);
  ch.u[1] = __builtin_amdgcn_perm(b3, b2, 0x07060302u);
  cl.u[0] = __builtin_amdgcn_perm(__float_as_uint(l1), __float_as_uint(l0), 0x07060302u);
  cl.u[1] = __builtin_amdgcn_perm(__float_as_uint(l3), __float_as_uint(l2), 0x07060302u);
  hi = ch.v; lo = cl.v;
}

// ---------------------------------------------------------------------------
// prep bodies (fused into prep_all: 9 launches -> 5)
// ---------------------------------------------------------------------------
__device__ void transpose_body(const float* __restrict__ in, ushort* __restrict__ out,
                               int R, int C, int Cout, int bx, int by, int tid) {
  __shared__ float t[32][33];
  const int c0 = bx * 32, r0 = by * 32;
  const int tx = tid & 31, ty = tid >> 5;
  for (int rr = ty; rr < 32; rr += 8) {
    int r = r0 + rr, c = c0 + tx;
    float v = 0.0f;
    if (r < R && c < C) v = in[(long)r * C + c];
    t[rr][tx] = v;
  }
  __syncthreads();
  for (int rr = ty; rr < 32; rr += 8) {
    int c = c0 + rr, r = r0 + tx;
    if (c < Cout && r < R) out[(long)c * R + r] = f2bf(t[tx][rr]);
  }
}

// ADMM setup -> MFMA operand form.
// W-state iteration (verified r6-r10): u = 2*clip(W)-W,
//   W' = base + T*u + (W - Z),  T = [[2Minv, G],[2*A12*Minv, A12*G]] (36x36)
//   base = T0*q per row,       T0 = [[Minv],[A12*Minv]] (36x24)
// Outputs row-major [n_out][k_in], bf16 hi+lo (rounded split):
// Th/Tl [48][64], T0h/T0l [48][32], bounds bl/bu [48].
__device__ void setup_body(const float* __restrict__ Aeq, const float* __restrict__ beq,
                           const float* __restrict__ A, const float* __restrict__ b,
                           const float* __restrict__ ub, const float* __restrict__ lb,
                           ushort* __restrict__ Th, ushort* __restrict__ Tl,
                           ushort* __restrict__ T0h, ushort* __restrict__ T0l,
                           float* __restrict__ blp, float* __restrict__ bup, int t) {
  __shared__ float Aug[24][48];
  __shared__ float A12[12 * 24];
  __shared__ float fac[24];
  __shared__ float Tx[24][36];
  for (int i = t; i < 48 * 64; i += 256) { Th[i] = 0; Tl[i] = 0; }
  for (int i = t; i < 48 * 32; i += 256) { T0h[i] = 0; T0l[i] = 0; }
  if (t < 96)  A12[t] = Aeq[t];
  if (t < 192) A12[96 + t] = A[t];
  __syncthreads();
  for (int idx = t; idx < 576; idx += 256) {
    int j = idx / 24, k = idx % 24;
    float s = (j == k) ? (1.0f + SIGMA_C + 2.0f * RHO_C) : 0.0f;
    for (int r = 0; r < 12; ++r) s += RHO_C * A12[r * 24 + j] * A12[r * 24 + k];
    Aug[j][k] = s;
    Aug[j][24 + k] = (j == k) ? 1.0f : 0.0f;
  }
  __syncthreads();
  for (int p = 0; p < 24; ++p) {
    float rp = 1.0f / Aug[p][p];
    if (t < 24) fac[t] = Aug[t][p];
    __syncthreads();
    if (t < 48) Aug[p][t] *= rp;
    __syncthreads();
    for (int idx = t; idx < 24 * 48; idx += 256) {
      int r = idx / 48, c = idx % 48;
      if (r != p) Aug[r][c] -= fac[r] * Aug[p][c];
    }
    __syncthreads();
  }
  auto splitStore = [](ushort* hp, ushort* lp, int i, float v) {
    ushort hs = f2bf(v);
    float hf = __uint_as_float(((uint)hs) << 16);
    ushort ls = f2bf(v - hf);
    hp[i] = hs; lp[i] = ls;
  };
  for (int idx = t; idx < 24 * 36; idx += 256) {
    int n = idx / 36, k = idx % 36;
    float v;
    if (k < 24) v = 2.0f * Aug[n][24 + k];
    else {
      v = 0.0f;
      for (int j = 0; j < 24; ++j) v += Aug[n][24 + j] * A12[(k - 24) * 24 + j];
    }
    Tx[n][k] = v;
    splitStore(Th, Tl, n * 64 + k, v);
  }
  __syncthreads();
  for (int idx = t; idx < 12 * 36; idx += 256) {
    int m = idx / 36, k = idx % 36;
    float v = 0.0f;
    for (int j = 0; j < 24; ++j) v += A12[m * 24 + j] * Tx[j][k];
    splitStore(Th, Tl, (24 + m) * 64 + k, v);
  }
  for (int idx = t; idx < 36 * 24; idx += 256) {
    int n = idx / 24, k = idx % 24;
    float v;
    if (n < 24) v = Aug[n][24 + k];
    else {
      v = 0.0f;
      for (int j = 0; j < 24; ++j) v += A12[(n - 24) * 24 + j] * Aug[j][24 + k];
    }
    splitStore(T0h, T0l, n * 32 + k, v);
  }
  if (t < 48) {
    float lv, uv;
    if (t < 24)      { lv = lb[t]; uv = ub[t]; }
    else if (t < 28) { lv = beq[t - 24]; uv = lv; }
    else if (t < 36) { lv = -1e30f; uv = b[t - 28]; }
    else             { lv = -1e30f; uv = 1e30f; }
    blp[t] = lv; bup[t] = uv;
  }
}

// Fused prep: [0,nConv) convert | [+512) W1T | [+1024) W2T | [+32) W3T | [1) setup
__global__ void prep_all(
    const float* __restrict__ state, ushort* __restrict__ stateB, int n4,
    const float* __restrict__ W1, ushort* __restrict__ W1T,
    const float* __restrict__ W2, ushort* __restrict__ W2T,
    const float* __restrict__ W3, ushort* __restrict__ W3T,
    const float* __restrict__ Aeq, const float* __restrict__ beq,
    const float* __restrict__ A, const float* __restrict__ b,
    const float* __restrict__ ub, const float* __restrict__ lb,
    ushort* __restrict__ Th, ushort* __restrict__ Tl,
    ushort* __restrict__ T0h, ushort* __restrict__ T0l,
    float* __restrict__ blp, float* __restrict__ bup) {
  const int nConv = n4 >> 8;
  int bb = blockIdx.x;
  if (bb < nConv) {
    int i = bb * 256 + threadIdx.x;
    if (i < n4) {
      float4 v = ((const float4*)state)[i];
      uint2 p;
      p.x = (uint)f2bf(v.x) | ((uint)f2bf(v.y) << 16);
      p.y = (uint)f2bf(v.z) | ((uint)f2bf(v.w) << 16);
      ((uint2*)stateB)[i] = p;
    }
    return;
  }
  bb -= nConv;
  if (bb < 512)  { transpose_body(W1, W1T, 512, 1024, 1024, bb & 31, bb >> 5, threadIdx.x); return; }
  bb -= 512;
  if (bb < 1024) { transpose_body(W2, W2T, 1024, 1024, 1024, bb & 31, bb >> 5, threadIdx.x); return; }
  bb -= 1024;
  if (bb < 32)   { transpose_body(W3, W3T, 1024, 24, 32, 0, bb, threadIdx.x); return; }
  setup_body(Aeq, beq, A, b, ub, lb, Th, Tl, T0h, T0l, blp, bup, threadIdx.x);
}

// ---------------------------------------------------------------------------
// bf16 GEMM, C = A[M,K] * Bt[N,K]^T — m97-style staging. Kept for the skinny
// final layer (N=24) only.
// ---------------------------------------------------------------------------
template<int BM, int BN, int WM, int WN, int TM, int TN, int MODE>
__global__ __launch_bounds__(256) void gemm_bt(
    const ushort* __restrict__ A, const ushort* __restrict__ Bt,
    const float* __restrict__ bias, void* __restrict__ Cout_,
    int K, int ldc, int nvalid) {
  __shared__ char lds[(BM + BN) * 64];
  char* ldsA = lds;
  char* ldsB = lds + BM * 64;

  const int tid = threadIdx.x;
  const int wave = tid >> 6;
  const int lane = tid & 63;
  const int blockM = blockIdx.y * BM;
  const int blockN = blockIdx.x * BN;
  const int wm = (wave / WN) * (TM * 16);
  const int wn = (wave % WN) * (TN * 16);

  f32x4 acc[TM][TN] = {};

  const int l15 = lane & 15;
  const int kq = lane >> 4;
  constexpr int AI = BM / 16;
  constexpr int TOT = (BM + BN) / 16;
  const int srow = lane >> 2;
  const int kb = (lane & 3) ^ ((srow >> 1) & 3);

  for (int k0 = 0; k0 < K; k0 += 32) {
    for (int inst = wave; inst < TOT; inst += 4) {
      const bool isA = inst < AI;
      const int i = isA ? inst : inst - AI;
      const ushort* gp = (isA ? A : Bt)
          + (long)((isA ? blockM : blockN) + i * 16 + srow) * K + (k0 + kb * 8);
      char* lp = (isA ? ldsA : ldsB) + i * 1024;
      gload_lds16(gp, lp);
    }
    __syncthreads();

    bf16x8 af[TM], bfr[TN];
#pragma unroll
    for (int i = 0; i < TM; ++i) {
      int r = wm + i * 16 + l15;
      int ch = kq ^ ((r >> 1) & 3);
      af[i] = *(const bf16x8*)(ldsA + r * 64 + ch * 16);
    }
#pragma unroll
    for (int j = 0; j < TN; ++j) {
      int r = wn + j * 16 + l15;
      int ch = kq ^ ((r >> 1) & 3);
      bfr[j] = *(const bf16x8*)(ldsB + r * 64 + ch * 16);
    }
#pragma unroll
    for (int i = 0; i < TM; ++i)
#pragma unroll
      for (int j = 0; j < TN; ++j)
        acc[i][j] = __builtin_amdgcn_mfma_f32_16x16x32_bf16(af[i], bfr[j], acc[i][j], 0, 0, 0);
    __syncthreads();
  }

  const int ro = lane >> 4;
#pragma unroll
  for (int i = 0; i < TM; ++i) {
#pragma unroll
    for (int j = 0; j < TN; ++j) {
      const int col = blockN + wn + j * 16 + l15;
      float bv;
      if (MODE == 0) bv = bias[col];
      else bv = (col < nvalid) ? bias[col] : 0.0f;
#pragma unroll
      for (int r = 0; r < 4; ++r) {
        const int row = blockM + wm + i * 16 + ro * 4 + r;
        float v = acc[i][j][r] + bv;
        if (MODE == 0) {
          v = fmaxf(v, 0.0f);
          ((ushort*)Cout_)[(long)row * ldc + col] = f2bf(v);
        } else {
          if (col < nvalid) ((float*)Cout_)[(long)row * ldc + col] = v;
        }
      }
    }
  }
}

// ---------------------------------------------------------------------------
// 256x256 8-phase bf16 GEMM (T1+T2+T3+T4+T5) — unchanged.
// ---------------------------------------------------------------------------
#define GEMM8P_QUAD(MI0, NJ0)                                                 \
  _Pragma("unroll") for (int mi_ = 0; mi_ < 4; ++mi_)                         \
  _Pragma("unroll") for (int nj_ = 0; nj_ < 2; ++nj_)                         \
  _Pragma("unroll") for (int kk_ = 0; kk_ < 2; ++kk_)                         \
    acc[(MI0) + mi_][(NJ0) + nj_] = __builtin_amdgcn_mfma_f32_16x16x32_bf16(  \
        aF[mi_][kk_], bF[(NJ0) + nj_][kk_], acc[(MI0) + mi_][(NJ0) + nj_],    \
        0, 0, 0);

#define GEMM8P_SYNC_PRE()                              \
  __builtin_amdgcn_s_barrier();                        \
  asm volatile("s_waitcnt lgkmcnt(0)" ::: "memory");   \
  __builtin_amdgcn_sched_barrier(0);                   \
  __builtin_amdgcn_s_setprio(1);

#define GEMM8P_SYNC_POST()                             \
  __builtin_amdgcn_s_setprio(0);                       \
  __builtin_amdgcn_s_barrier();

__global__ __launch_bounds__(512, 2) void gemm8p(
    const ushort* __restrict__ A, const ushort* __restrict__ Bt,
    const float* __restrict__ bias, ushort* __restrict__ Cout,
    int K, int ldc, int nblk_n) {
  __shared__ __align__(16) char ldsc[131072];   // [2 buf][A 32K | B 32K]

  const int nwg = gridDim.x;
  const int bid = blockIdx.x;
  const int swz = (bid & 7) * (nwg >> 3) + (bid >> 3);
  const int blockM = (swz / nblk_n) * 256;
  const int blockN = (swz % nblk_n) * 256;

  const int tid = threadIdx.x;
  const int wave = tid >> 6;
  const int lane = tid & 63;
  const int l15 = lane & 15;
  const int q = lane >> 4;
  const int wm = (wave >> 2) * 128;
  const int wn = (wave & 3) * 64;
  const int nt = K >> 6;

  f32x4 acc[8][4] = {};

  auto stage = [&](int ts, int h) {
    if (ts >= nt) return;
    char* base = ldsc + ((ts & 1) << 16) + (h << 14);
#pragma unroll
    for (int j = 0; j < 2; ++j) {
      const int idx = wave * 64 + j * 512 + lane;
      const int row = idx >> 3;
      const int cs = (idx & 7) ^ (row & 7);
      const ushort* gp =
          (h < 2 ? A + (long)(blockM + ((h & 1) << 7) + row) * K
                 : Bt + (long)(blockN + ((h & 1) << 7) + row) * K)
          + (ts << 6) + cs * 8;
      gload_lds16(gp, base + ((wave * 64 + j * 512) << 4));
    }
  };
  auto dsA = [&](int cb, int mi, int kk) {
    const int r = wm + mi * 16 + l15;
    const int cs = (kk * 4 + q) ^ (r & 7);
    return *(const bf16x8*)(ldsc + (cb << 16) + r * 128 + cs * 16);
  };
  auto dsB = [&](int cb, int nj, int kk) {
    const int r = wn + nj * 16 + l15;
    const int cs = (kk * 4 + q) ^ (r & 7);
    return *(const bf16x8*)(ldsc + (cb << 16) + 32768 + r * 128 + cs * 16);
  };

  stage(0, 0); stage(0, 1); stage(0, 2); stage(0, 3);
  stage(1, 0);
  asm volatile("s_waitcnt vmcnt(2)" ::: "memory");
  __builtin_amdgcn_s_barrier();

  bf16x8 aF[4][2], bF[4][2];
#pragma unroll 1
  for (int t = 0; t < nt; ++t) {
    const int cb = t & 1;
#pragma unroll
    for (int mi = 0; mi < 4; ++mi)
#pragma unroll
      for (int kk = 0; kk < 2; ++kk) aF[mi][kk] = dsA(cb, mi, kk);
#pragma unroll
    for (int nj = 0; nj < 2; ++nj)
#pragma unroll
      for (int kk = 0; kk < 2; ++kk) bF[nj][kk] = dsB(cb, nj, kk);
    stage(t + 1, 1);
    GEMM8P_SYNC_PRE();
    GEMM8P_QUAD(0, 0);
    GEMM8P_SYNC_POST();
#pragma unroll
    for (int nj = 2; nj < 4; ++nj)
#pragma unroll
      for (int kk = 0; kk < 2; ++kk) bF[nj][kk] = dsB(cb, nj, kk);
    stage(t + 1, 2);
    GEMM8P_SYNC_PRE();
    GEMM8P_QUAD(0, 2);
    GEMM8P_SYNC_POST();
#pragma unroll
    for (int mi = 0; mi < 4; ++mi)
#pragma unroll
      for (int kk = 0; kk < 2; ++kk) aF[mi][kk] = dsA(cb, 4 + mi, kk);
    stage(t + 1, 3);
    GEMM8P_SYNC_PRE();
    GEMM8P_QUAD(4, 2);
    GEMM8P_SYNC_POST();
    stage(t + 2, 0);
    if (t + 2 < nt) { asm volatile("s_waitcnt vmcnt(2)" ::: "memory"); }
    else            { asm volatile("s_waitcnt vmcnt(0)" ::: "memory"); }
    __builtin_amdgcn_s_barrier();
    __builtin_amdgcn_s_setprio(1);
    GEMM8P_QUAD(4, 0);
    GEMM8P_SYNC_POST();
  }

#pragma unroll
  for (int mi = 0; mi < 8; ++mi) {
#pragma unroll
    for (int nj = 0; nj < 4; ++nj) {
      const int col = blockN + wn + nj * 16 + l15;
      const float bv = bias[col];
#pragma unroll
      for (int r = 0; r < 4; ++r) {
        const int row = blockM + wm + mi * 16 + q * 4 + r;
        float v = acc[mi][nj][r] + bv;
        v = fmaxf(v, 0.0f);
        Cout[(long)row * ldc + col] = f2bf(v);
      }
    }
  }
}

// ---------------------------------------------------------------------------
// ADMM via MFMA, register-only loop.
// SWAPPED operands: state Wt[n][b] = D(col=l15=batch b, row=4q+r=n within
// tile t: n = 16t+4q+r), computed as D = mfma(A=T-frag, B=u-frag).
// With 16x16x16 MFMA the B-fragment k-distribution (k=4q+j) EQUALS the
// D-row distribution (row=4q+r) -> u chunk c's B-fragment IS tile t=c's
// register block. No LDS, no transpose, no cross-lane movement in the loop.
// Round-2 post-mortem: plain launch_bounds(256) let the allocator cap at 68
// VGPRs < ~130 live set -> T-fragments reloaded from memory EVERY iteration
// in a 1-wave/SIMD serial chain (VALUBusy 58%, MfmaUtil 27%). Fix:
// launch_bounds(256,1) (512-VGPR budget; grid is 1 wave/SIMD regardless)
// + v_perm-based splitPack4 (12 VALU/pack vs ~24, bit-identical).
// ---------------------------------------------------------------------------
#define MFMA16(a, b, c) __builtin_amdgcn_mfma_f32_16x16x16bf16_1k(a, b, c, 0, 0, 0)

__global__ __launch_bounds__(256, 1) void admm_mfma(
    const float* __restrict__ raw,
    const ushort* __restrict__ Th, const ushort* __restrict__ Tl,
    const ushort* __restrict__ T0h, const ushort* __restrict__ T0l,
    const float* __restrict__ blp, const float* __restrict__ bup,
    float* __restrict__ outp) {
  const int tid = threadIdx.x, wave = tid >> 6, lane = tid & 63;
  const int l15 = lane & 15, q = lane >> 4;
  const long rowbase = (long)blockIdx.x * 64 + wave * 16;

  // bounds for n = 16t + 4q + r
  f32x4 bl[3], bu[3];
#pragma unroll
  for (int t = 0; t < 3; ++t) {
    bl[t] = *(const f32x4*)(blp + 16 * t + 4 * q);
    bu[t] = *(const f32x4*)(bup + 16 * t + 4 * q);
  }

  // ---- peel: base = W_1 = T0 * q^T (16x16x32, A=T0-frag, B=raw-frag) -----
  f32x4 W[3], base[3];
  {
    bf16x8 t0h[3], t0l[3];
#pragma unroll
    for (int t = 0; t < 3; ++t) {
      t0h[t] = *(const bf16x8*)(T0h + (16 * t + l15) * 32 + q * 8);
      t0l[t] = *(const bf16x8*)(T0l + (16 * t + l15) * 32 + q * 8);
    }
    float qa[8];
    if (q < 3) {
      const float* rp = raw + (rowbase + l15) * 24 + q * 8;
      float4 v0 = *(const float4*)rp;
      float4 v1 = *(const float4*)(rp + 4);
      qa[0] = v0.x; qa[1] = v0.y; qa[2] = v0.z; qa[3] = v0.w;
      qa[4] = v1.x; qa[5] = v1.y; qa[6] = v1.z; qa[7] = v1.w;
    } else {
#pragma unroll
      for (int j = 0; j < 8; ++j) qa[j] = 0.0f;
    }
    bf16x8 qhi, qlo;
    splitPack(qa, qhi, qlo);
#pragma unroll
    for (int t = 0; t < 3; ++t) {
      f32x4 acc = {0.0f, 0.0f, 0.0f, 0.0f};
      acc = __builtin_amdgcn_mfma_f32_16x16x32_bf16(t0h[t], qhi, acc, 0, 0, 0);
      acc = __builtin_amdgcn_mfma_f32_16x16x32_bf16(t0h[t], qlo, acc, 0, 0, 0);
      acc = __builtin_amdgcn_mfma_f32_16x16x32_bf16(t0l[t], qhi, acc, 0, 0, 0);
      base[t] = acc; W[t] = acc;
    }
  }

  // ---- T A-fragments for 16x16x16: th[t][c] = T[16t+l15][16c+4q+j] --------
  bf16x4 th[3][3], tl[3][3];
#pragma unroll
  for (int t = 0; t < 3; ++t)
#pragma unroll
    for (int c = 0; c < 3; ++c) {
      th[t][c] = *(const bf16x4*)(Th + (16 * t + l15) * 64 + 16 * c + 4 * q);
      tl[t][c] = *(const bf16x4*)(Tl + (16 * t + l15) * 64 + 16 * c + 4 * q);
    }

  f32x4 y01[2];
#pragma unroll 1
  for (int it = 1; it < ADMM_ITERS; ++it) {
    bf16x4 uh[3], ul[3];
    f32x4 C[3];
#pragma unroll
    for (int t = 0; t < 3; ++t) {
      f32x4 u;
#pragma unroll
      for (int r = 0; r < 4; ++r) {
        float w = W[t][r];
        float z = fminf(fmaxf(w, bl[t][r]), bu[t][r]);
        float yy = w - z;
        u[r] = z - yy;                 // = 2z - w
        C[t][r] = base[t][r] + yy;
        if (t < 2) y01[t][r] = yy;
      }
      splitPack4(u, uh[t], ul[t]);
    }
#pragma unroll
    for (int t = 0; t < 3; ++t) {
      f32x4 a0 = C[t];
      f32x4 a1 = {0.0f, 0.0f, 0.0f, 0.0f};
      f32x4 a2 = {0.0f, 0.0f, 0.0f, 0.0f};
      a0 = MFMA16(th[t][0], uh[0], a0);
      a0 = MFMA16(th[t][0], ul[0], a0);
      a0 = MFMA16(tl[t][0], uh[0], a0);
      a1 = MFMA16(th[t][1], uh[1], a1);
      a1 = MFMA16(th[t][1], ul[1], a1);
      a1 = MFMA16(tl[t][1], uh[1], a1);
      a2 = MFMA16(th[t][2], uh[2], a2);
      a2 = MFMA16(th[t][2], ul[2], a2);
      a2 = MFMA16(tl[t][2], uh[2], a2);
      W[t] = (a0 + a1) + a2;
    }
  }

  // X_100 = W_100 - (W_99 - Z_99); cols n = 16t+4q+r < 24
#pragma unroll
  for (int t = 0; t < 2; ++t) {
    if (t == 0 || q < 2) {
      f32x4 x;
#pragma unroll
      for (int r = 0; r < 4; ++r) x[r] = W[t][r] - y01[t][r];
      *(f32x4*)(outp + (rowbase + l15) * 24 + 16 * t + 4 * q) = x;
    }
  }
}

// ---------------------------------------------------------------------------
extern "C" void kernel_launch(void* const* d_in, const int* in_sizes, int n_in,
                              void* d_out, int out_size, void* d_ws, size_t ws_size,
                              hipStream_t stream) {
  const float* state = (const float*)d_in[0];
  const float* Aeq   = (const float*)d_in[1];
  const float* beq   = (const float*)d_in[2];
  const float* Ain   = (const float*)d_in[3];
  const float* bin   = (const float*)d_in[4];
  const float* ub    = (const float*)d_in[5];
  const float* lb    = (const float*)d_in[6];
  const float* W1    = (const float*)d_in[7];
  const float* b1    = (const float*)d_in[8];
  const float* W2    = (const float*)d_in[9];
  const float* b2    = (const float*)d_in[10];
  const float* W3    = (const float*)d_in[11];
  const float* b3    = (const float*)d_in[12];

  const int Bn = in_sizes[0] / 512;            // 16384
  char* ws = (char*)d_ws;
  ushort* stateB = (ushort*)(ws + 0);          // 16384x512 bf16  (16 MB)
  ushort* W1T    = (ushort*)(ws + 16777216);   // 1024x512        (1 MB)
  ushort* W2T    = (ushort*)(ws + 17825792);   // 1024x1024       (2 MB)
  ushort* W3T    = (ushort*)(ws + 19922944);   // 32x1024 (rows>=24 zero)
  ushort* Th     = (ushort*)(ws + 19993600);   // 48x64 bf16 hi
  ushort* Tl     = (ushort*)(ws + 19999744);   // 48x64 bf16 lo
  ushort* T0h    = (ushort*)(ws + 20005888);   // 48x32 bf16 hi
  ushort* T0l    = (ushort*)(ws + 20008960);   // 48x32 bf16 lo
  float*  blp    = (float*) (ws + 20012032);   // 48
  float*  bup    = (float*) (ws + 20012224);   // 48
  ushort* H1     = (ushort*)(ws + 21565440);   // 16384x1024 bf16 (32 MB)
  ushort* H2     = (ushort*)(ws + 55119872);   // 16384x1024 bf16 (32 MB)
  float*  rawb   = (float*)d_out;              // gemm3 out = admm in (in-place)

  const int n4 = (Bn * 512) / 4;
  const int nConv = n4 / 256;                  // 8192
  const int nPrep = nConv + 512 + 1024 + 32 + 1;
  prep_all<<<nPrep, 256, 0, stream>>>(state, stateB, n4, W1, W1T, W2, W2T, W3, W3T,
                                      Aeq, beq, Ain, bin, ub, lb,
                                      Th, Tl, T0h, T0l, blp, bup);

  const int nblkN = 1024 / 256;                // 4
  const int nwg = (Bn / 256) * nblkN;          // 256 (div by 8 -> swizzle ok)
  gemm8p<<<nwg, 512, 0, stream>>>(stateB, W1T, b1, H1, 512, 1024, nblkN);
  gemm8p<<<nwg, 512, 0, stream>>>(H1, W2T, b2, H2, 1024, 1024, nblkN);
  gemm_bt<64, 32, 4, 1, 1, 2, 1><<<dim3(1, Bn / 64), 256, 0, stream>>>(
      H2, W3T, b3, rawb, 1024, 24, 24);

  admm_mfma<<<Bn / 64, 256, 0, stream>>>(rawb, Th, Tl, T0h, T0l, blp, bup,
                                         (float*)d_out);
}

// Round 4
// 250.681 us; speedup vs baseline: 1.0229x; 1.0229x over previous
//
#include <hip/hip_runtime.h>

using uint = unsigned int;
using ushort = unsigned short;

typedef __attribute__((ext_vector_type(8))) short bf16x8;
typedef __attribute__((ext_vector_type(4))) short bf16x4;
typedef __attribute__((ext_vector_type(4))) float f32x4;

#define ADMM_ITERS 100
#define RHO_C 1.0f
#define SIGMA_C 1e-6f

__device__ inline ushort f2bf(float f) {
  union { float f; uint u; } c; c.f = f;
  uint u = c.u;
  uint r = (u + 0x7fffu + ((u >> 16) & 1u)) >> 16;
  return (ushort)r;
}

__device__ inline void gload_lds16(const void* g, void* l) {
  __builtin_amdgcn_global_load_lds(
      (const __attribute__((address_space(1))) void*)g,
      (__attribute__((address_space(3))) void*)l, 16, 0, 0);
}

// Split 8 f32 -> hi/lo bf16x8 by TRUNCATION (hi = mantissa-masked; lo = exact
// residual, truncated). Residual error ~2^-16 relative.
__device__ inline void splitPack(const float* x, bf16x8& hi, bf16x8& lo) {
#pragma unroll
  for (int j = 0; j < 8; ++j) {
    uint b = __float_as_uint(x[j]);
    uint hb = b & 0xffff0000u;
    float lf = x[j] - __uint_as_float(hb);
    hi[j] = (short)(b >> 16);
    lo[j] = (short)(__float_as_uint(lf) >> 16);
  }
}

// 4-wide truncation split with explicit v_perm_b32 packing (bit-identical to
// splitPack, ~12 VALU instead of ~24: perm grabs hi16 of two f32s per instr).
__device__ inline void splitPack4(const f32x4& x, bf16x4& hi, bf16x4& lo) {
  uint b0 = __float_as_uint(x[0]), b1 = __float_as_uint(x[1]);
  uint b2 = __float_as_uint(x[2]), b3 = __float_as_uint(x[3]);
  float l0 = x[0] - __uint_as_float(b0 & 0xffff0000u);
  float l1 = x[1] - __uint_as_float(b1 & 0xffff0000u);
  float l2 = x[2] - __uint_as_float(b2 & 0xffff0000u);
  float l3 = x[3] - __uint_as_float(b3 & 0xffff0000u);
  union { uint u[2]; bf16x4 v; } ch, cl;
  ch.u[0] = __builtin_amdgcn_perm(b1, b0, 0x07060302u);
  ch.u[1] = __builtin_amdgcn_perm(b3, b2, 0x07060302u);
  cl.u[0] = __builtin_amdgcn_perm(__float_as_uint(l1), __float_as_uint(l0), 0x07060302u);
  cl.u[1] = __builtin_amdgcn_perm(__float_as_uint(l3), __float_as_uint(l2), 0x07060302u);
  hi = ch.v; lo = cl.v;
}

// ---------------------------------------------------------------------------
// prep bodies (fused into prep_all: 9 launches -> 5)
// ---------------------------------------------------------------------------
__device__ void transpose_body(const float* __restrict__ in, ushort* __restrict__ out,
                               int R, int C, int Cout, int bx, int by, int tid) {
  __shared__ float t[32][33];
  const int c0 = bx * 32, r0 = by * 32;
  const int tx = tid & 31, ty = tid >> 5;
  for (int rr = ty; rr < 32; rr += 8) {
    int r = r0 + rr, c = c0 + tx;
    float v = 0.0f;
    if (r < R && c < C) v = in[(long)r * C + c];
    t[rr][tx] = v;
  }
  __syncthreads();
  for (int rr = ty; rr < 32; rr += 8) {
    int c = c0 + rr, r = r0 + tx;
    if (c < Cout && r < R) out[(long)c * R + r] = f2bf(t[tx][rr]);
  }
}

// ADMM setup -> MFMA operand form.
// W-state iteration (verified r6-r10): u = 2*clip(W)-W,
//   W' = base + T*u + (W - Z),  T = [[2Minv, G],[2*A12*Minv, A12*G]] (36x36)
//   base = T0*q per row,       T0 = [[Minv],[A12*Minv]] (36x24)
// Outputs row-major [n_out][k_in], bf16 hi+lo (rounded split):
// Th/Tl [48][64], T0h/T0l [48][32], bounds bl/bu [48].
__device__ void setup_body(const float* __restrict__ Aeq, const float* __restrict__ beq,
                           const float* __restrict__ A, const float* __restrict__ b,
                           const float* __restrict__ ub, const float* __restrict__ lb,
                           ushort* __restrict__ Th, ushort* __restrict__ Tl,
                           ushort* __restrict__ T0h, ushort* __restrict__ T0l,
                           float* __restrict__ blp, float* __restrict__ bup, int t) {
  __shared__ float Aug[24][48];
  __shared__ float A12[12 * 24];
  __shared__ float fac[24];
  __shared__ float Tx[24][36];
  for (int i = t; i < 48 * 64; i += 256) { Th[i] = 0; Tl[i] = 0; }
  for (int i = t; i < 48 * 32; i += 256) { T0h[i] = 0; T0l[i] = 0; }
  if (t < 96)  A12[t] = Aeq[t];
  if (t < 192) A12[96 + t] = A[t];
  __syncthreads();
  for (int idx = t; idx < 576; idx += 256) {
    int j = idx / 24, k = idx % 24;
    float s = (j == k) ? (1.0f + SIGMA_C + 2.0f * RHO_C) : 0.0f;
    for (int r = 0; r < 12; ++r) s += RHO_C * A12[r * 24 + j] * A12[r * 24 + k];
    Aug[j][k] = s;
    Aug[j][24 + k] = (j == k) ? 1.0f : 0.0f;
  }
  __syncthreads();
  for (int p = 0; p < 24; ++p) {
    float rp = 1.0f / Aug[p][p];
    if (t < 24) fac[t] = Aug[t][p];
    __syncthreads();
    if (t < 48) Aug[p][t] *= rp;
    __syncthreads();
    for (int idx = t; idx < 24 * 48; idx += 256) {
      int r = idx / 48, c = idx % 48;
      if (r != p) Aug[r][c] -= fac[r] * Aug[p][c];
    }
    __syncthreads();
  }
  auto splitStore = [](ushort* hp, ushort* lp, int i, float v) {
    ushort hs = f2bf(v);
    float hf = __uint_as_float(((uint)hs) << 16);
    ushort ls = f2bf(v - hf);
    hp[i] = hs; lp[i] = ls;
  };
  for (int idx = t; idx < 24 * 36; idx += 256) {
    int n = idx / 36, k = idx % 36;
    float v;
    if (k < 24) v = 2.0f * Aug[n][24 + k];
    else {
      v = 0.0f;
      for (int j = 0; j < 24; ++j) v += Aug[n][24 + j] * A12[(k - 24) * 24 + j];
    }
    Tx[n][k] = v;
    splitStore(Th, Tl, n * 64 + k, v);
  }
  __syncthreads();
  for (int idx = t; idx < 12 * 36; idx += 256) {
    int m = idx / 36, k = idx % 36;
    float v = 0.0f;
    for (int j = 0; j < 24; ++j) v += A12[m * 24 + j] * Tx[j][k];
    splitStore(Th, Tl, (24 + m) * 64 + k, v);
  }
  for (int idx = t; idx < 36 * 24; idx += 256) {
    int n = idx / 24, k = idx % 24;
    float v;
    if (n < 24) v = Aug[n][24 + k];
    else {
      v = 0.0f;
      for (int j = 0; j < 24; ++j) v += A12[(n - 24) * 24 + j] * Aug[j][24 + k];
    }
    splitStore(T0h, T0l, n * 32 + k, v);
  }
  if (t < 48) {
    float lv, uv;
    if (t < 24)      { lv = lb[t]; uv = ub[t]; }
    else if (t < 28) { lv = beq[t - 24]; uv = lv; }
    else if (t < 36) { lv = -1e30f; uv = b[t - 28]; }
    else             { lv = -1e30f; uv = 1e30f; }
    blp[t] = lv; bup[t] = uv;
  }
}

// Fused prep: [0,nConv) convert | [+512) W1T | [+1024) W2T | [+32) W3T | [1) setup
__global__ void prep_all(
    const float* __restrict__ state, ushort* __restrict__ stateB, int n4,
    const float* __restrict__ W1, ushort* __restrict__ W1T,
    const float* __restrict__ W2, ushort* __restrict__ W2T,
    const float* __restrict__ W3, ushort* __restrict__ W3T,
    const float* __restrict__ Aeq, const float* __restrict__ beq,
    const float* __restrict__ A, const float* __restrict__ b,
    const float* __restrict__ ub, const float* __restrict__ lb,
    ushort* __restrict__ Th, ushort* __restrict__ Tl,
    ushort* __restrict__ T0h, ushort* __restrict__ T0l,
    float* __restrict__ blp, float* __restrict__ bup) {
  const int nConv = n4 >> 8;
  int bb = blockIdx.x;
  if (bb < nConv) {
    int i = bb * 256 + threadIdx.x;
    if (i < n4) {
      float4 v = ((const float4*)state)[i];
      uint2 p;
      p.x = (uint)f2bf(v.x) | ((uint)f2bf(v.y) << 16);
      p.y = (uint)f2bf(v.z) | ((uint)f2bf(v.w) << 16);
      ((uint2*)stateB)[i] = p;
    }
    return;
  }
  bb -= nConv;
  if (bb < 512)  { transpose_body(W1, W1T, 512, 1024, 1024, bb & 31, bb >> 5, threadIdx.x); return; }
  bb -= 512;
  if (bb < 1024) { transpose_body(W2, W2T, 1024, 1024, 1024, bb & 31, bb >> 5, threadIdx.x); return; }
  bb -= 1024;
  if (bb < 32)   { transpose_body(W3, W3T, 1024, 24, 32, 0, bb, threadIdx.x); return; }
  setup_body(Aeq, beq, A, b, ub, lb, Th, Tl, T0h, T0l, blp, bup, threadIdx.x);
}

// ---------------------------------------------------------------------------
// bf16 GEMM, C = A[M,K] * Bt[N,K]^T — m97-style staging. Kept for the skinny
// final layer (N=24) only.
// ---------------------------------------------------------------------------
template<int BM, int BN, int WM, int WN, int TM, int TN, int MODE>
__global__ __launch_bounds__(256) void gemm_bt(
    const ushort* __restrict__ A, const ushort* __restrict__ Bt,
    const float* __restrict__ bias, void* __restrict__ Cout_,
    int K, int ldc, int nvalid) {
  __shared__ char lds[(BM + BN) * 64];
  char* ldsA = lds;
  char* ldsB = lds + BM * 64;

  const int tid = threadIdx.x;
  const int wave = tid >> 6;
  const int lane = tid & 63;
  const int blockM = blockIdx.y * BM;
  const int blockN = blockIdx.x * BN;
  const int wm = (wave / WN) * (TM * 16);
  const int wn = (wave % WN) * (TN * 16);

  f32x4 acc[TM][TN] = {};

  const int l15 = lane & 15;
  const int kq = lane >> 4;
  constexpr int AI = BM / 16;
  constexpr int TOT = (BM + BN) / 16;
  const int srow = lane >> 2;
  const int kb = (lane & 3) ^ ((srow >> 1) & 3);

  for (int k0 = 0; k0 < K; k0 += 32) {
    for (int inst = wave; inst < TOT; inst += 4) {
      const bool isA = inst < AI;
      const int i = isA ? inst : inst - AI;
      const ushort* gp = (isA ? A : Bt)
          + (long)((isA ? blockM : blockN) + i * 16 + srow) * K + (k0 + kb * 8);
      char* lp = (isA ? ldsA : ldsB) + i * 1024;
      gload_lds16(gp, lp);
    }
    __syncthreads();

    bf16x8 af[TM], bfr[TN];
#pragma unroll
    for (int i = 0; i < TM; ++i) {
      int r = wm + i * 16 + l15;
      int ch = kq ^ ((r >> 1) & 3);
      af[i] = *(const bf16x8*)(ldsA + r * 64 + ch * 16);
    }
#pragma unroll
    for (int j = 0; j < TN; ++j) {
      int r = wn + j * 16 + l15;
      int ch = kq ^ ((r >> 1) & 3);
      bfr[j] = *(const bf16x8*)(ldsB + r * 64 + ch * 16);
    }
#pragma unroll
    for (int i = 0; i < TM; ++i)
#pragma unroll
      for (int j = 0; j < TN; ++j)
        acc[i][j] = __builtin_amdgcn_mfma_f32_16x16x32_bf16(af[i], bfr[j], acc[i][j], 0, 0, 0);
    __syncthreads();
  }

  const int ro = lane >> 4;
#pragma unroll
  for (int i = 0; i < TM; ++i) {
#pragma unroll
    for (int j = 0; j < TN; ++j) {
      const int col = blockN + wn + j * 16 + l15;
      float bv;
      if (MODE == 0) bv = bias[col];
      else bv = (col < nvalid) ? bias[col] : 0.0f;
#pragma unroll
      for (int r = 0; r < 4; ++r) {
        const int row = blockM + wm + i * 16 + ro * 4 + r;
        float v = acc[i][j][r] + bv;
        if (MODE == 0) {
          v = fmaxf(v, 0.0f);
          ((ushort*)Cout_)[(long)row * ldc + col] = f2bf(v);
        } else {
          if (col < nvalid) ((float*)Cout_)[(long)row * ldc + col] = v;
        }
      }
    }
  }
}

// ---------------------------------------------------------------------------
// 256x256 8-phase bf16 GEMM (T1+T2+T3+T4+T5) — unchanged.
// ---------------------------------------------------------------------------
#define GEMM8P_QUAD(MI0, NJ0)                                                 \
  _Pragma("unroll") for (int mi_ = 0; mi_ < 4; ++mi_)                         \
  _Pragma("unroll") for (int nj_ = 0; nj_ < 2; ++nj_)                         \
  _Pragma("unroll") for (int kk_ = 0; kk_ < 2; ++kk_)                         \
    acc[(MI0) + mi_][(NJ0) + nj_] = __builtin_amdgcn_mfma_f32_16x16x32_bf16(  \
        aF[mi_][kk_], bF[(NJ0) + nj_][kk_], acc[(MI0) + mi_][(NJ0) + nj_],    \
        0, 0, 0);

#define GEMM8P_SYNC_PRE()                              \
  __builtin_amdgcn_s_barrier();                        \
  asm volatile("s_waitcnt lgkmcnt(0)" ::: "memory");   \
  __builtin_amdgcn_sched_barrier(0);                   \
  __builtin_amdgcn_s_setprio(1);

#define GEMM8P_SYNC_POST()                             \
  __builtin_amdgcn_s_setprio(0);                       \
  __builtin_amdgcn_s_barrier();

__global__ __launch_bounds__(512, 2) void gemm8p(
    const ushort* __restrict__ A, const ushort* __restrict__ Bt,
    const float* __restrict__ bias, ushort* __restrict__ Cout,
    int K, int ldc, int nblk_n) {
  __shared__ __align__(16) char ldsc[131072];   // [2 buf][A 32K | B 32K]

  const int nwg = gridDim.x;
  const int bid = blockIdx.x;
  const int swz = (bid & 7) * (nwg >> 3) + (bid >> 3);
  const int blockM = (swz / nblk_n) * 256;
  const int blockN = (swz % nblk_n) * 256;

  const int tid = threadIdx.x;
  const int wave = tid >> 6;
  const int lane = tid & 63;
  const int l15 = lane & 15;
  const int q = lane >> 4;
  const int wm = (wave >> 2) * 128;
  const int wn = (wave & 3) * 64;
  const int nt = K >> 6;

  f32x4 acc[8][4] = {};

  auto stage = [&](int ts, int h) {
    if (ts >= nt) return;
    char* base = ldsc + ((ts & 1) << 16) + (h << 14);
#pragma unroll
    for (int j = 0; j < 2; ++j) {
      const int idx = wave * 64 + j * 512 + lane;
      const int row = idx >> 3;
      const int cs = (idx & 7) ^ (row & 7);
      const ushort* gp =
          (h < 2 ? A + (long)(blockM + ((h & 1) << 7) + row) * K
                 : Bt + (long)(blockN + ((h & 1) << 7) + row) * K)
          + (ts << 6) + cs * 8;
      gload_lds16(gp, base + ((wave * 64 + j * 512) << 4));
    }
  };
  auto dsA = [&](int cb, int mi, int kk) {
    const int r = wm + mi * 16 + l15;
    const int cs = (kk * 4 + q) ^ (r & 7);
    return *(const bf16x8*)(ldsc + (cb << 16) + r * 128 + cs * 16);
  };
  auto dsB = [&](int cb, int nj, int kk) {
    const int r = wn + nj * 16 + l15;
    const int cs = (kk * 4 + q) ^ (r & 7);
    return *(const bf16x8*)(ldsc + (cb << 16) + 32768 + r * 128 + cs * 16);
  };

  stage(0, 0); stage(0, 1); stage(0, 2); stage(0, 3);
  stage(1, 0);
  asm volatile("s_waitcnt vmcnt(2)" ::: "memory");
  __builtin_amdgcn_s_barrier();

  bf16x8 aF[4][2], bF[4][2];
#pragma unroll 1
  for (int t = 0; t < nt; ++t) {
    const int cb = t & 1;
#pragma unroll
    for (int mi = 0; mi < 4; ++mi)
#pragma unroll
      for (int kk = 0; kk < 2; ++kk) aF[mi][kk] = dsA(cb, mi, kk);
#pragma unroll
    for (int nj = 0; nj < 2; ++nj)
#pragma unroll
      for (int kk = 0; kk < 2; ++kk) bF[nj][kk] = dsB(cb, nj, kk);
    stage(t + 1, 1);
    GEMM8P_SYNC_PRE();
    GEMM8P_QUAD(0, 0);
    GEMM8P_SYNC_POST();
#pragma unroll
    for (int nj = 2; nj < 4; ++nj)
#pragma unroll
      for (int kk = 0; kk < 2; ++kk) bF[nj][kk] = dsB(cb, nj, kk);
    stage(t + 1, 2);
    GEMM8P_SYNC_PRE();
    GEMM8P_QUAD(0, 2);
    GEMM8P_SYNC_POST();
#pragma unroll
    for (int mi = 0; mi < 4; ++mi)
#pragma unroll
      for (int kk = 0; kk < 2; ++kk) aF[mi][kk] = dsA(cb, 4 + mi, kk);
    stage(t + 1, 3);
    GEMM8P_SYNC_PRE();
    GEMM8P_QUAD(4, 2);
    GEMM8P_SYNC_POST();
    stage(t + 2, 0);
    if (t + 2 < nt) { asm volatile("s_waitcnt vmcnt(2)" ::: "memory"); }
    else            { asm volatile("s_waitcnt vmcnt(0)" ::: "memory"); }
    __builtin_amdgcn_s_barrier();
    __builtin_amdgcn_s_setprio(1);
    GEMM8P_QUAD(4, 0);
    GEMM8P_SYNC_POST();
  }

#pragma unroll
  for (int mi = 0; mi < 8; ++mi) {
#pragma unroll
    for (int nj = 0; nj < 4; ++nj) {
      const int col = blockN + wn + nj * 16 + l15;
      const float bv = bias[col];
#pragma unroll
      for (int r = 0; r < 4; ++r) {
        const int row = blockM + wm + mi * 16 + q * 4 + r;
        float v = acc[mi][nj][r] + bv;
        v = fmaxf(v, 0.0f);
        Cout[(long)row * ldc + col] = f2bf(v);
      }
    }
  }
}

// ---------------------------------------------------------------------------
// ADMM via MFMA, register-only loop, software-pipelined (round-4).
// SWAPPED operands: state Wt[n][b] = D(col=l15=batch b, row=4q+r=n), computed
// as D = mfma(A=T-frag, B=u-frag). With 16x16x16 MFMA the B-fragment
// k-distribution (k=4q+j) EQUALS the D-row distribution (row=4q+r), so u's
// B-fragment IS the previous MFMA register block. No LDS / cross-lane.
// Round-3 post-mortem: 1570 cy/iter at 1 wave/SIMD; MfmaUtil => ~15cy per
// MFMA (should be ~4): per-tile 3-deep MFMA chains issued back-to-back stall
// the in-order wave on every dependent issue; no other wave to fill bubbles.
// Round-4: (a) round-robin the 9 independent chains (t-major per k-step);
// (b) interleave: pack(t0) | chunk0 MFMAs | pack(t1) | chunk1 | pack(t2) |
// chunk2 | adds — each MFMA group has the next pack's ~32 independent VALU
// adjacent. Chunk-2 accumulator inits to C[t]=base+yy (available after all
// packs). (c) X_100 = base + T*u_99: loop does 98 updates, epilogue does the
// last update with acc2 init = base (yy cancels) — y01 copies gone.
// ---------------------------------------------------------------------------
#define MFMA16(a, b, c) __builtin_amdgcn_mfma_f32_16x16x16bf16_1k(a, b, c, 0, 0, 0)

__global__ __launch_bounds__(256) void admm_mfma(
    const float* __restrict__ raw,
    const ushort* __restrict__ Th, const ushort* __restrict__ Tl,
    const ushort* __restrict__ T0h, const ushort* __restrict__ T0l,
    const float* __restrict__ blp, const float* __restrict__ bup,
    float* __restrict__ outp) {
  const int tid = threadIdx.x, wave = tid >> 6, lane = tid & 63;
  const int l15 = lane & 15, q = lane >> 4;
  const long rowbase = (long)blockIdx.x * 64 + wave * 16;

  // bounds for n = 16t + 4q + r
  f32x4 bl[3], bu[3];
#pragma unroll
  for (int t = 0; t < 3; ++t) {
    bl[t] = *(const f32x4*)(blp + 16 * t + 4 * q);
    bu[t] = *(const f32x4*)(bup + 16 * t + 4 * q);
  }

  // ---- peel: base = W_1 = T0 * q^T (16x16x32, A=T0-frag, B=raw-frag) -----
  f32x4 W[3], base[3];
  {
    bf16x8 t0h[3], t0l[3];
#pragma unroll
    for (int t = 0; t < 3; ++t) {
      t0h[t] = *(const bf16x8*)(T0h + (16 * t + l15) * 32 + q * 8);
      t0l[t] = *(const bf16x8*)(T0l + (16 * t + l15) * 32 + q * 8);
    }
    float qa[8];
    if (q < 3) {
      const float* rp = raw + (rowbase + l15) * 24 + q * 8;
      float4 v0 = *(const float4*)rp;
      float4 v1 = *(const float4*)(rp + 4);
      qa[0] = v0.x; qa[1] = v0.y; qa[2] = v0.z; qa[3] = v0.w;
      qa[4] = v1.x; qa[5] = v1.y; qa[6] = v1.z; qa[7] = v1.w;
    } else {
#pragma unroll
      for (int j = 0; j < 8; ++j) qa[j] = 0.0f;
    }
    bf16x8 qhi, qlo;
    splitPack(qa, qhi, qlo);
#pragma unroll
    for (int t = 0; t < 3; ++t) {
      f32x4 acc = {0.0f, 0.0f, 0.0f, 0.0f};
      acc = __builtin_amdgcn_mfma_f32_16x16x32_bf16(t0h[t], qhi, acc, 0, 0, 0);
      acc = __builtin_amdgcn_mfma_f32_16x16x32_bf16(t0h[t], qlo, acc, 0, 0, 0);
      acc = __builtin_amdgcn_mfma_f32_16x16x32_bf16(t0l[t], qhi, acc, 0, 0, 0);
      base[t] = acc; W[t] = acc;
    }
  }

  // ---- T A-fragments for 16x16x16: th[t][c] = T[16t+l15][16c+4q+j] --------
  bf16x4 th[3][3], tl[3][3];
#pragma unroll
  for (int t = 0; t < 3; ++t)
#pragma unroll
    for (int c = 0; c < 3; ++c) {
      th[t][c] = *(const bf16x4*)(Th + (16 * t + l15) * 64 + 16 * c + 4 * q);
      tl[t][c] = *(const bf16x4*)(Tl + (16 * t + l15) * 64 + 16 * c + 4 * q);
    }

  // pack tile t from W[t]: u -> (uh,ul), C = base + (W - Z)
#define PACKT(t, UH, UL, CC)                                         \
  {                                                                  \
    f32x4 u_;                                                        \
    _Pragma("unroll") for (int r = 0; r < 4; ++r) {                  \
      float w_ = W[t][r];                                            \
      float z_ = fminf(fmaxf(w_, bl[t][r]), bu[t][r]);               \
      float yy_ = w_ - z_;                                           \
      u_[r] = z_ - yy_;                                              \
      CC[r] = base[t][r] + yy_;                                      \
    }                                                                \
    splitPack4(u_, UH, UL);                                          \
  }

  const f32x4 z4 = {0.0f, 0.0f, 0.0f, 0.0f};

#pragma unroll 1
  for (int it = 2; it < ADMM_ITERS; ++it) {   // 98 updates: W_1 -> W_99
    bf16x4 uh0, ul0, uh1, ul1, uh2, ul2;
    f32x4 C0, C1, C2;
    f32x4 a00, a10, a20, a01, a11, a21, a02, a12, a22;

    PACKT(0, uh0, ul0, C0);
    // chunk 0 (init 0), round-robin over t per k-step
    a00 = MFMA16(th[0][0], uh0, z4);
    a10 = MFMA16(th[1][0], uh0, z4);
    a20 = MFMA16(th[2][0], uh0, z4);
    a00 = MFMA16(th[0][0], ul0, a00);
    a10 = MFMA16(th[1][0], ul0, a10);
    a20 = MFMA16(th[2][0], ul0, a20);
    a00 = MFMA16(tl[0][0], uh0, a00);
    a10 = MFMA16(tl[1][0], uh0, a10);
    a20 = MFMA16(tl[2][0], uh0, a20);

    PACKT(1, uh1, ul1, C1);
    a01 = MFMA16(th[0][1], uh1, z4);
    a11 = MFMA16(th[1][1], uh1, z4);
    a21 = MFMA16(th[2][1], uh1, z4);
    a01 = MFMA16(th[0][1], ul1, a01);
    a11 = MFMA16(th[1][1], ul1, a11);
    a21 = MFMA16(th[2][1], ul1, a21);
    a01 = MFMA16(tl[0][1], uh1, a01);
    a11 = MFMA16(tl[1][1], uh1, a11);
    a21 = MFMA16(tl[2][1], uh1, a21);

    PACKT(2, uh2, ul2, C2);
    // chunk 2 accumulators carry C[t] = base + yy
    a02 = MFMA16(th[0][2], uh2, C0);
    a12 = MFMA16(th[1][2], uh2, C1);
    a22 = MFMA16(th[2][2], uh2, C2);
    a02 = MFMA16(th[0][2], ul2, a02);
    a12 = MFMA16(th[1][2], ul2, a12);
    a22 = MFMA16(th[2][2], ul2, a22);
    a02 = MFMA16(tl[0][2], uh2, a02);
    a12 = MFMA16(tl[1][2], uh2, a12);
    a22 = MFMA16(tl[2][2], uh2, a22);

    W[0] = (a00 + a01) + a02;
    W[1] = (a10 + a11) + a12;
    W[2] = (a20 + a21) + a22;
  }

  // ---- epilogue: X_100 = base + T*u_99 (yy cancels); only tiles 0,1 -------
  {
    bf16x4 uh0, ul0, uh1, ul1, uh2, ul2;
    f32x4 C0, C1, C2;    // computed but only u needed; C dead for t>=0 here
    PACKT(0, uh0, ul0, C0);
    PACKT(1, uh1, ul1, C1);
    PACKT(2, uh2, ul2, C2);
    f32x4 x00, x10, x01, x11, x02, x12;
    x00 = MFMA16(th[0][0], uh0, z4);
    x10 = MFMA16(th[1][0], uh0, z4);
    x00 = MFMA16(th[0][0], ul0, x00);
    x10 = MFMA16(th[1][0], ul0, x10);
    x00 = MFMA16(tl[0][0], uh0, x00);
    x10 = MFMA16(tl[1][0], uh0, x10);
    x01 = MFMA16(th[0][1], uh1, z4);
    x11 = MFMA16(th[1][1], uh1, z4);
    x01 = MFMA16(th[0][1], ul1, x01);
    x11 = MFMA16(th[1][1], ul1, x11);
    x01 = MFMA16(tl[0][1], uh1, x01);
    x11 = MFMA16(tl[1][1], uh1, x11);
    x02 = MFMA16(th[0][2], uh2, base[0]);
    x12 = MFMA16(th[1][2], uh2, base[1]);
    x02 = MFMA16(th[0][2], ul2, x02);
    x12 = MFMA16(th[1][2], ul2, x12);
    x02 = MFMA16(tl[0][2], uh2, x02);
    x12 = MFMA16(tl[1][2], uh2, x12);
    f32x4 X0 = (x00 + x01) + x02;
    f32x4 X1 = (x10 + x11) + x12;
    *(f32x4*)(outp + (rowbase + l15) * 24 + 4 * q) = X0;
    if (q < 2) *(f32x4*)(outp + (rowbase + l15) * 24 + 16 + 4 * q) = X1;
  }
#undef PACKT
}

// ---------------------------------------------------------------------------
extern "C" void kernel_launch(void* const* d_in, const int* in_sizes, int n_in,
                              void* d_out, int out_size, void* d_ws, size_t ws_size,
                              hipStream_t stream) {
  const float* state = (const float*)d_in[0];
  const float* Aeq   = (const float*)d_in[1];
  const float* beq   = (const float*)d_in[2];
  const float* Ain   = (const float*)d_in[3];
  const float* bin   = (const float*)d_in[4];
  const float* ub    = (const float*)d_in[5];
  const float* lb    = (const float*)d_in[6];
  const float* W1    = (const float*)d_in[7];
  const float* b1    = (const float*)d_in[8];
  const float* W2    = (const float*)d_in[9];
  const float* b2    = (const float*)d_in[10];
  const float* W3    = (const float*)d_in[11];
  const float* b3    = (const float*)d_in[12];

  const int Bn = in_sizes[0] / 512;            // 16384
  char* ws = (char*)d_ws;
  ushort* stateB = (ushort*)(ws + 0);          // 16384x512 bf16  (16 MB)
  ushort* W1T    = (ushort*)(ws + 16777216);   // 1024x512        (1 MB)
  ushort* W2T    = (ushort*)(ws + 17825792);   // 1024x1024       (2 MB)
  ushort* W3T    = (ushort*)(ws + 19922944);   // 32x1024 (rows>=24 zero)
  ushort* Th     = (ushort*)(ws + 19993600);   // 48x64 bf16 hi
  ushort* Tl     = (ushort*)(ws + 19999744);   // 48x64 bf16 lo
  ushort* T0h    = (ushort*)(ws + 20005888);   // 48x32 bf16 hi
  ushort* T0l    = (ushort*)(ws + 20008960);   // 48x32 bf16 lo
  float*  blp    = (float*) (ws + 20012032);   // 48
  float*  bup    = (float*) (ws + 20012224);   // 48
  ushort* H1     = (ushort*)(ws + 21565440);   // 16384x1024 bf16 (32 MB)
  ushort* H2     = (ushort*)(ws + 55119872);   // 16384x1024 bf16 (32 MB)
  float*  rawb   = (float*)d_out;              // gemm3 out = admm in (in-place)

  const int n4 = (Bn * 512) / 4;
  const int nConv = n4 / 256;                  // 8192
  const int nPrep = nConv + 512 + 1024 + 32 + 1;
  prep_all<<<nPrep, 256, 0, stream>>>(state, stateB, n4, W1, W1T, W2, W2T, W3, W3T,
                                      Aeq, beq, Ain, bin, ub, lb,
                                      Th, Tl, T0h, T0l, blp, bup);

  const int nblkN = 1024 / 256;                // 4
  const int nwg = (Bn / 256) * nblkN;          // 256 (div by 8 -> swizzle ok)
  gemm8p<<<nwg, 512, 0, stream>>>(stateB, W1T, b1, H1, 512, 1024, nblkN);
  gemm8p<<<nwg, 512, 0, stream>>>(H1, W2T, b2, H2, 1024, 1024, nblkN);
  gemm_bt<64, 32, 4, 1, 1, 2, 1><<<dim3(1, Bn / 64), 256, 0, stream>>>(
      H2, W3T, b3, rawb, 1024, 24, 24);

  admm_mfma<<<Bn / 64, 256, 0, stream>>>(rawb, Th, Tl, T0h, T0l, blp, bup,
                                         (float*)d_out);
}